// Round 20
// baseline (200.581 us; speedup 1.0000x reference)
//
#include <hip/hip_runtime.h>
#include <hip/hip_bf16.h>
#include <cstdint>

#define DM   1024
#define NH   16
#define DKK  64
#define BB   4
#define SS   2048

typedef __attribute__((ext_vector_type(8)))  short short8;
typedef __attribute__((ext_vector_type(4)))  float f32x4;
typedef __attribute__((ext_vector_type(16))) float f32x16;

__device__ __forceinline__ unsigned short f2bf(float f) {
    union { float f; uint32_t u; } v; v.f = f;
    uint32_t u = v.u;
    uint32_t r = (u + 0x7FFFu + ((u >> 16) & 1u)) >> 16;   // RNE
    return (unsigned short)r;
}

#define GLL(src, dst) __builtin_amdgcn_global_load_lds(                      \
        (__attribute__((address_space(1))) void*)(src),                      \
        (__attribute__((address_space(3))) void*)(dst), 16, 0, 0)

// ---------------- fp32 -> bf16 convert + PRE-SWIZZLE (4 weight matrices) ----------------
// W_sw[j][kb*8..] = W[j][kbs*8..], kbs = (kb&~7)|((kb^j)&7)
__global__ void cvt_w(const float* __restrict__ wq, const float* __restrict__ wk,
                      const float* __restrict__ wv, const float* __restrict__ wo,
                      unsigned short* __restrict__ dst)
{
    int i = blockIdx.x * 256 + threadIdx.x;      // 16B-block id: 4 * 1024 * 128
    int a = i >> 17;
    int r = i & 131071;
    int j = r >> 7, kb = r & 127;
    int kbs = (kb & ~7) | ((kb ^ j) & 7);
    const float* s = (a == 0 ? wq : a == 1 ? wk : a == 2 ? wv : wo) + (size_t)j * 1024 + kbs * 8;
    float4 f0 = *(const float4*)(s);
    float4 f1 = *(const float4*)(s + 4);
    union { uint32_t u[4]; short8 s8; } c;
    asm("v_cvt_pk_bf16_f32 %0, %1, %2" : "=v"(c.u[0]) : "v"(f0.x), "v"(f0.y));
    asm("v_cvt_pk_bf16_f32 %0, %1, %2" : "=v"(c.u[1]) : "v"(f0.z), "v"(f0.w));
    asm("v_cvt_pk_bf16_f32 %0, %1, %2" : "=v"(c.u[2]) : "v"(f1.x), "v"(f1.y));
    asm("v_cvt_pk_bf16_f32 %0, %1, %2" : "=v"(c.u[3]) : "v"(f1.z), "v"(f1.w));
    *(short8*)(dst + ((size_t)a << 20) + (size_t)j * 1024 + kb * 8) = c.s8;
}

// -------- merged QKV GEMM: producer-consumer waves, fused fp32-A conversion --------
// 384 thr = 6 waves. Waves 0-3: MFMA consumers (64x64 C quadrants). Waves 4-5: producers
// stage tile t+1 (A: fp32 loads -> cvt_pk -> XOR-swizzled lA write; B: 8 GLLs, linear,
// W pre-swizzled) while consumers compute tile t. One __syncthreads per iter publishes
// buf[(t+1)&1]; consumers' reads of buf[t&1] complete before their barrier arrival, and
// producers only overwrite buf[t&1] in iter t+1 (after that barrier) -> race-free.
__global__ __launch_bounds__(384) void gemm_qkv(
        const float* __restrict__ Aq, const float* __restrict__ Ak, const float* __restrict__ Av,
        const unsigned short* __restrict__ Wq, const unsigned short* __restrict__ Wk,
        const unsigned short* __restrict__ Wv,
        const float* __restrict__ bq, const float* __restrict__ bk, const float* __restrict__ bv,
        unsigned short* __restrict__ Qo, unsigned short* __restrict__ Ko,
        unsigned short* __restrict__ Vo, const float qscale)
{
    const int orig = blockIdx.z * 512 + blockIdx.y * 8 + blockIdx.x;
    const int wid  = (orig & 7) * 192 + (orig >> 3);   // bijective XCD swizzle (1536%8==0)
    const int z    = wid >> 9;
    const int rem  = wid & 511;
    const int brow = (rem >> 3) * 128;
    const int bcol = (rem & 7) * 128;

    const float* Af          = (z == 0) ? Aq : (z == 1) ? Ak : Av;
    const unsigned short* Bw = (z == 0) ? Wq : (z == 1) ? Wk : Wv;
    const float* bias        = (z == 0) ? bq : (z == 1) ? bk : bv;

    __shared__ __align__(16) unsigned short lA[2][128 * 64];   // bf16, XOR-swizzled rows
    __shared__ __align__(16) unsigned short lB[2][128 * 64];   // bf16, linear (W pre-swz)

    const int tid = threadIdx.x;
    const int w = tid >> 6, l = tid & 63;
    const int wr = (w >> 1) * 64, wc = (w & 1) * 64;   // consumer quadrant (w<4)
    const int lrow = l & 15;
    const int hi = l >> 4;

    f32x4 acc[4][4] = {};

    if (w >= 4) {
        // ---------------- producer path (128 threads) ----------------
        const int p = tid - 256;                       // 0..127
        // stage(t, buf): A rows brow..+127, cols t*64..+63
        auto stage = [&](int t, int buf) {
            float4 fa[16];
#pragma unroll
            for (int j = 0; j < 8; ++j) {              // A: 8 pairs of float4
                const int pr = j * 128 + p;
                const int row = pr >> 3, pb8 = pr & 7;
                const float* ga = Af + (size_t)(brow + row) * 1024 + t * 64 + pb8 * 8;
                fa[2 * j]     = *(const float4*)(ga);
                fa[2 * j + 1] = *(const float4*)(ga + 4);
            }
#pragma unroll
            for (int j = 0; j < 8; ++j) {              // B: 8 GLLs, linear dest
                const int c = j * 128 + p;
                const int row = c >> 3, kb = c & 7;
                GLL(Bw + (size_t)(bcol + row) * 1024 + t * 64 + kb * 8, lB[buf] + c * 8);
            }
#pragma unroll
            for (int j = 0; j < 8; ++j) {              // cvt + swizzled ds_write
                const int pr = j * 128 + p;
                const int row = pr >> 3, pb8 = pr & 7;
                union { uint32_t u[4]; short8 s8; } c8;
                asm("v_cvt_pk_bf16_f32 %0, %1, %2" : "=v"(c8.u[0]) : "v"(fa[2*j][0]), "v"(fa[2*j][1]));
                asm("v_cvt_pk_bf16_f32 %0, %1, %2" : "=v"(c8.u[1]) : "v"(fa[2*j][2]), "v"(fa[2*j][3]));
                asm("v_cvt_pk_bf16_f32 %0, %1, %2" : "=v"(c8.u[2]) : "v"(fa[2*j+1][0]), "v"(fa[2*j+1][1]));
                asm("v_cvt_pk_bf16_f32 %0, %1, %2" : "=v"(c8.u[3]) : "v"(fa[2*j+1][2]), "v"(fa[2*j+1][3]));
                *(short8*)((char*)lA[buf] + row * 128 + ((pb8 ^ (row & 7)) << 4)) = c8.s8;
            }
        };
        stage(0, 0);
        __syncthreads();                               // B0 (drains vm+lgkm for all)
        for (int t = 0; t < 16; ++t) {
            if (t < 15) stage(t + 1, (t + 1) & 1);
            __syncthreads();
        }
        return;                                        // producers: no epilogue
    }

    // ---------------- consumer path (waves 0-3) ----------------
    __syncthreads();                                   // B0: tile 0 published
    for (int t = 0; t < 16; ++t) {
        const char* la_ = (const char*)lA[t & 1];
        const char* lb_ = (const char*)lB[t & 1];
        __builtin_amdgcn_s_setprio(1);
#pragma unroll
        for (int kk = 0; kk < 2; ++kk) {
            short8 af[4], bf[4];
#pragma unroll
            for (int m = 0; m < 4; ++m) {
                const int row = wr + m * 16 + lrow;
                const int pb = (kk * 4 + hi) ^ (row & 7);
                af[m] = *(const short8*)(la_ + row * 128 + (pb << 4));
            }
#pragma unroll
            for (int n = 0; n < 4; ++n) {
                const int row = wc + n * 16 + lrow;
                const int pb = (kk * 4 + hi) ^ (row & 7);
                bf[n] = *(const short8*)(lb_ + row * 128 + (pb << 4));
            }
#pragma unroll
            for (int m = 0; m < 4; ++m)
#pragma unroll
                for (int n = 0; n < 4; ++n)
                    acc[m][n] = __builtin_amdgcn_mfma_f32_16x16x32_bf16(af[m], bf[n], acc[m][n], 0, 0, 0);
        }
        __builtin_amdgcn_s_setprio(0);
        __syncthreads();
    }

    const float ascale = (z == 0) ? qscale : 1.0f;
#pragma unroll
    for (int m = 0; m < 4; ++m) {
#pragma unroll
        for (int n = 0; n < 4; ++n) {
            const int i0 = brow + wr + m * 16 + hi * 4;
            const int j  = bcol + wc + n * 16 + lrow;
            const float bj = bias[j];
            const int hh = j >> 6, d = j & 63;
            if (z < 2) {
                unsigned short* Cb = (z == 0) ? Qo : Ko;
#pragma unroll
                for (int t = 0; t < 4; ++t) {
                    const int i = i0 + t;
                    const int b = i >> 11, s = i & 2047;
                    Cb[(((size_t)(b * NH + hh) * SS) + s) * DKK + d] = f2bf((acc[m][n][t] + bj) * ascale);
                }
            } else {   // V^T
                const int b = i0 >> 11, s0 = i0 & 2047;
                ushort4 pk;
                pk.x = f2bf(acc[m][n][0] + bj);
                pk.y = f2bf(acc[m][n][1] + bj);
                pk.z = f2bf(acc[m][n][2] + bj);
                pk.w = f2bf(acc[m][n][3] + bj);
                *(ushort4*)(Vo + (((size_t)(b * NH + hh) * DKK) + d) * SS + s0) = pk;
            }
        }
    }
}

// ---------------- final projection GEMM: bf16 A reg-staged swizzled, depth-2, fp32 out ------
__global__ __launch_bounds__(256) void gemm_out(
        const unsigned short* __restrict__ A,
        const unsigned short* __restrict__ Bw,
        const float* __restrict__ bias,
        float* __restrict__ Cout)
{
    const int orig = blockIdx.y * 8 + blockIdx.x;
    const int wid  = (orig & 7) * 64 + (orig >> 3);
    const int brow = (wid >> 3) * 128;
    const int bcol = (wid & 7) * 128;

    __shared__ __align__(16) unsigned short lA[128 * 64];
    __shared__ __align__(16) unsigned short lB[2][128 * 64];

    const int tid = threadIdx.x;
    const int w = tid >> 6, l = tid & 63;
    const int wr = (w >> 1) * 64, wc = (w & 1) * 64;
    const int lrow = l & 15;
    const int hi = l >> 4;
    const int sr = l >> 3, scb = l & 7;

    const unsigned short* aga[4];
    const unsigned short* bga[4];
    int awb[4], lbo[4];
#pragma unroll
    for (int i = 0; i < 4; ++i) {
        const int chunk = w * 4 + i;
        const int r = chunk * 8 + sr;
        aga[i] = A  + (size_t)(brow + r) * 1024 + scb * 8;
        bga[i] = Bw + (size_t)(bcol + r) * 1024 + scb * 8;
        awb[i] = chunk * 1024 + sr * 128 + ((scb ^ sr) << 4);
        lbo[i] = chunk * 512;
    }

    short8 aX[4], aY[4];
    f32x4 acc[4][4] = {};

#pragma unroll
    for (int i = 0; i < 4; ++i) GLL(bga[i], lB[0] + lbo[i]);
#pragma unroll
    for (int i = 0; i < 4; ++i) aX[i] = *(const short8*)(aga[i]);
#pragma unroll
    for (int i = 0; i < 4; ++i) aY[i] = *(const short8*)(aga[i] + 64);

#define OUT_WR(CUR)                                                     \
    _Pragma("unroll")                                                   \
    for (int i = 0; i < 4; ++i)                                         \
        *(short8*)((char*)lA + awb[i]) = CUR[i];

#define OUT_MFMA(LB)                                                                              \
    {                                                                                             \
        const unsigned short* lb = (LB);                                                          \
        __builtin_amdgcn_s_setprio(1);                                                            \
        _Pragma("unroll")                                                                         \
        for (int kk = 0; kk < 2; ++kk) {                                                          \
            short8 af[4], bf[4];                                                                  \
            _Pragma("unroll")                                                                     \
            for (int m = 0; m < 4; ++m) {                                                         \
                const int row = wr + m * 16 + lrow;                                               \
                const int pb = (kk * 4 + hi) ^ (row & 7);                                         \
                af[m] = *(const short8*)((const char*)lA + row * 128 + (pb << 4));                \
            }                                                                                     \
            _Pragma("unroll")                                                                     \
            for (int n = 0; n < 4; ++n) {                                                         \
                const int row = wc + n * 16 + lrow;                                               \
                const int pb = (kk * 4 + hi) ^ (row & 7);                                         \
                bf[n] = *(const short8*)((const char*)lb + row * 128 + (pb << 4));                \
            }                                                                                     \
            _Pragma("unroll")                                                                     \
            for (int m = 0; m < 4; ++m)                                                           \
                _Pragma("unroll")                                                                 \
                for (int n = 0; n < 4; ++n)                                                       \
                    acc[m][n] = __builtin_amdgcn_mfma_f32_16x16x32_bf16(af[m], bf[n], acc[m][n], 0, 0, 0); \
        }                                                                                         \
        __builtin_amdgcn_s_setprio(0);                                                            \
    }

    for (int t = 0; t < 14; t += 2) {
        OUT_WR(aX);
        {
            const int ko = (t + 2) * 64;
#pragma unroll
            for (int i = 0; i < 4; ++i) aX[i] = *(const short8*)(aga[i] + ko);
            const int kb = (t + 1) * 64;
#pragma unroll
            for (int i = 0; i < 4; ++i) GLL(bga[i] + kb, lB[1] + lbo[i]);
        }
        asm volatile("s_waitcnt vmcnt(8) lgkmcnt(0)" ::: "memory");
        __builtin_amdgcn_s_barrier();
        OUT_MFMA(lB[0]);
        asm volatile("" ::: "memory");
        __builtin_amdgcn_s_barrier();

        OUT_WR(aY);
        {
            const int ko = (t + 3) * 64;
#pragma unroll
            for (int i = 0; i < 4; ++i) aY[i] = *(const short8*)(aga[i] + ko);
            const int kb = (t + 2) * 64;
#pragma unroll
            for (int i = 0; i < 4; ++i) GLL(bga[i] + kb, lB[0] + lbo[i]);
        }
        asm volatile("s_waitcnt vmcnt(8) lgkmcnt(0)" ::: "memory");
        __builtin_amdgcn_s_barrier();
        OUT_MFMA(lB[1]);
        asm volatile("" ::: "memory");
        __builtin_amdgcn_s_barrier();
    }
    OUT_WR(aX);
#pragma unroll
    for (int i = 0; i < 4; ++i) GLL(bga[i] + 15 * 64, lB[1] + lbo[i]);
    asm volatile("s_waitcnt vmcnt(4) lgkmcnt(0)" ::: "memory");
    __builtin_amdgcn_s_barrier();
    OUT_MFMA(lB[0]);
    asm volatile("" ::: "memory");
    __builtin_amdgcn_s_barrier();
    OUT_WR(aY);
    asm volatile("s_waitcnt vmcnt(0) lgkmcnt(0)" ::: "memory");
    __builtin_amdgcn_s_barrier();
    OUT_MFMA(lB[1]);

#pragma unroll
    for (int m = 0; m < 4; ++m) {
#pragma unroll
        for (int n = 0; n < 4; ++n) {
            const int i0 = brow + wr + m * 16 + (l >> 4) * 4;
            const int j  = bcol + wc + n * 16 + lrow;
            const float bj = bias[j];
#pragma unroll
            for (int t = 0; t < 4; ++t)
                Cout[(size_t)(i0 + t) * DM + j] = acc[m][n][t] + bj;
        }
    }
#undef OUT_WR
#undef OUT_MFMA
}

// ---------------- causal flash attention (round-7, unchanged) ----------------
__global__ __launch_bounds__(256) void attn_kernel(
        const unsigned short* __restrict__ Q,
        const unsigned short* __restrict__ K,
        const unsigned short* __restrict__ Vt,
        unsigned short* __restrict__ AO)
{
    const int flat = blockIdx.y * 16 + blockIdx.x;      // grid (16, 64)
    const int r8 = flat & 7, k8 = flat >> 3;
    const int bh = r8 * 8 + (k8 & 7);                   // 8 heads per XCD-residue (L2 share)
    const int qchunk = 15 - (k8 >> 3);                  // LPT: long blocks first
    const int tid = threadIdx.x;
    const int w = tid >> 6, l = tid & 63;
    const int ln = l & 31, h = l >> 5;
    const int qb = qchunk * 128;
    const int q0w = qb + w * 32;

    __shared__ __align__(16) char lK[2][4096];
    __shared__ __align__(16) char lV[2][4096];

    const unsigned short* Qp = Q  + ((size_t)bh * SS + q0w) * DKK;
    const unsigned short* Kp = K  + (size_t)bh * SS * DKK;
    const unsigned short* Vp = Vt + (size_t)bh * DKK * SS;

    const int srow = tid >> 3, scb = tid & 7;
    const int swb = srow * 128 + ((scb * 16) ^ ((srow & 7) << 4));
    const unsigned short* ksrc = Kp + srow * DKK + scb * 8;            // + t*2048
    const int vd = (scb < 4) ? srow : (srow + 32);
    const unsigned short* vsrc = Vp + (size_t)vd * SS + (scb & 3) * 8; // + t*32

    int ka[4], va[4];
#pragma unroll
    for (int ks = 0; ks < 4; ++ks)
        ka[ks] = ln * 128 + ((ks * 32 + h * 16) ^ ((ln & 7) << 4));
#pragma unroll
    for (int c = 0; c < 4; ++c)
        va[c] = ln * 128 + ((c * 32 + h * 16) ^ ((ln & 7) << 4));

    short8 qf[4];
#pragma unroll
    for (int ks = 0; ks < 4; ++ks)
        qf[ks] = *(const short8*)(Qp + (size_t)ln * DKK + ks * 16 + h * 8);

    f32x16 o0 = {}, o1 = {};
    float lsum = 0.f;

    const int Tc = qb / 32;
    const int NT = Tc + 4;

    auto compute = [&](int t, int buf) {
        const char* kb = lK[buf];
        const char* vb = lV[buf];
        short8 kf[4];
#pragma unroll
        for (int ks = 0; ks < 4; ++ks) kf[ks] = *(const short8*)(kb + ka[ks]);

        f32x16 s = {};
        __builtin_amdgcn_s_setprio(1);
#pragma unroll
        for (int ks = 0; ks < 4; ++ks)
            s = __builtin_amdgcn_mfma_f32_32x32x16_bf16(kf[ks], qf[ks], s, 0, 0, 0);
        __builtin_amdgcn_s_setprio(0);

        const bool diag = (t == Tc + w);
#pragma unroll
        for (int r = 0; r < 16; ++r) {
            float e;
            asm("v_exp_f32 %0, %1" : "=v"(e) : "v"(s[r]));   // 2^s (Q pre-scaled)
            if (diag) {
                const int crow = (r & 3) + 8 * (r >> 2) + 4 * h;
                e = (crow > ln) ? 0.f : e;
            }
            s[r] = e;
            lsum += e;
        }

        uint32_t pk[8];
#pragma unroll
        for (int i = 0; i < 8; ++i) {
            uint32_t d;
            asm("v_cvt_pk_bf16_f32 %0, %1, %2" : "=v"(d) : "v"(s[2 * i]), "v"(s[2 * i + 1]));
            pk[i] = d;
        }
        asm("v_permlane32_swap_b32 %0, %1" : "+v"(pk[0]), "+v"(pk[2]));
        asm("v_permlane32_swap_b32 %0, %1" : "+v"(pk[1]), "+v"(pk[3]));
        asm("v_permlane32_swap_b32 %0, %1" : "+v"(pk[4]), "+v"(pk[6]));
        asm("v_permlane32_swap_b32 %0, %1" : "+v"(pk[5]), "+v"(pk[7]));

        union Ux { uint32_t u[4]; short8 s8; } pa0, pa1;
        pa0.u[0] = pk[0]; pa0.u[1] = pk[1]; pa0.u[2] = pk[2]; pa0.u[3] = pk[3];
        pa1.u[0] = pk[4]; pa1.u[1] = pk[5]; pa1.u[2] = pk[6]; pa1.u[3] = pk[7];

        short8 vf00 = *(const short8*)(vb + va[0]);
        short8 vf10 = *(const short8*)(vb + va[1]);
        short8 vf01 = *(const short8*)(vb + va[2]);
        short8 vf11 = *(const short8*)(vb + va[3]);

        __builtin_amdgcn_s_setprio(1);
        o0 = __builtin_amdgcn_mfma_f32_32x32x16_bf16(pa0.s8, vf00, o0, 0, 0, 0);
        o0 = __builtin_amdgcn_mfma_f32_32x32x16_bf16(pa1.s8, vf10, o0, 0, 0, 0);
        o1 = __builtin_amdgcn_mfma_f32_32x32x16_bf16(pa0.s8, vf01, o1, 0, 0, 0);
        o1 = __builtin_amdgcn_mfma_f32_32x32x16_bf16(pa1.s8, vf11, o1, 0, 0, 0);
        __builtin_amdgcn_s_setprio(0);
    };

    short8 kA = *(const short8*)(ksrc);
    short8 vA = *(const short8*)(vsrc);
    *(short8*)(&lK[0][swb]) = kA;
    *(short8*)(&lV[0][swb]) = vA;
    kA = *(const short8*)(ksrc + 2048);
    vA = *(const short8*)(vsrc + 32);
    short8 kB = {}, vB = {};
    __syncthreads();

    int t = 0, buf = 0;
    for (;;) {
        if (t + 2 < NT) {
            kB = *(const short8*)(ksrc + (size_t)(t + 2) * 2048);
            vB = *(const short8*)(vsrc + (size_t)(t + 2) * 32);
        }
        if (t <= Tc + w) compute(t, buf);
        if (t + 1 < NT) {
            *(short8*)(&lK[buf ^ 1][swb]) = kA;
            *(short8*)(&lV[buf ^ 1][swb]) = vA;
        }
        __syncthreads();
        buf ^= 1;
        if (++t == NT) break;

        if (t + 2 < NT) {
            kA = *(const short8*)(ksrc + (size_t)(t + 2) * 2048);
            vA = *(const short8*)(vsrc + (size_t)(t + 2) * 32);
        }
        if (t <= Tc + w) compute(t, buf);
        if (t + 1 < NT) {
            *(short8*)(&lK[buf ^ 1][swb]) = kB;
            *(short8*)(&lV[buf ^ 1][swb]) = vB;
        }
        __syncthreads();
        buf ^= 1;
        if (++t == NT) break;
    }

    lsum += __shfl_xor(lsum, 32, 64);
    const float rcp = 1.0f / lsum;

    const int bb = bh >> 4, hh = bh & 15;
#pragma unroll
    for (int r = 0; r < 16; ++r) {
        const int crow = (r & 3) + 8 * (r >> 2) + 4 * h;
        const float rl = __shfl(rcp, crow, 64);
        const size_t row = (size_t)(bb * SS + q0w + crow) * DM + hh * DKK;
        AO[row + ln]      = f2bf(o0[r] * rl);
        AO[row + 32 + ln] = f2bf(o1[r] * rl);
    }
}

extern "C" void kernel_launch(void* const* d_in, const int* in_sizes, int n_in,
                              void* d_out, int out_size, void* d_ws, size_t ws_size,
                              hipStream_t stream)
{
    const float* query  = (const float*)d_in[0];
    const float* key_in = (const float*)d_in[1];
    const float* value  = (const float*)d_in[2];
    const float* Wq = (const float*)d_in[3];
    const float* bq = (const float*)d_in[4];
    const float* Wk = (const float*)d_in[5];
    const float* bk = (const float*)d_in[6];
    const float* Wv = (const float*)d_in[7];
    const float* bv = (const float*)d_in[8];
    const float* Wo = (const float*)d_in[9];
    const float* bo = (const float*)d_in[10];

    const size_t NACT = (size_t)BB * SS * DM;   // 8388608
    const size_t NWT  = (size_t)DM * DM;        // 1048576

    unsigned short* ws  = (unsigned short*)d_ws;
    unsigned short* wqb = ws;
    unsigned short* wkb = wqb + NWT;
    unsigned short* wvb = wkb + NWT;
    unsigned short* wob = wvb + NWT;
    unsigned short* Qb  = wob + NWT;
    unsigned short* Kb  = Qb + NACT;
    unsigned short* Vtb = Kb + NACT;
    unsigned short* AOb = Vtb + NACT;

    cvt_w<<<2048, 256, 0, stream>>>(Wq, Wk, Wv, Wo, ws);

    const float QSCALE = 0.125f * 1.44269504088896f;   // 1/sqrt(64) * log2(e)
    dim3 gq(8, 64, 3);   // 1536 blocks
    gemm_qkv<<<gq, 384, 0, stream>>>(query, key_in, value, wqb, wkb, wvb,
                                     bq, bk, bv, Qb, Kb, Vtb, QSCALE);

    attn_kernel<<<dim3(16, 64), 256, 0, stream>>>(Qb, Kb, Vtb, AOb);

    dim3 gg(DM / 128, (BB * SS) / 128);   // (8, 64)
    gemm_out<<<gg, 256, 0, stream>>>(AOb, wob, bo, (float*)d_out);
}

// Round 21
// 176.624 us; speedup vs baseline: 1.1356x; 1.1356x over previous
//
#include <hip/hip_runtime.h>
#include <hip/hip_bf16.h>
#include <cstdint>

#define DM   1024
#define NH   16
#define DKK  64
#define BB   4
#define SS   2048

typedef __attribute__((ext_vector_type(8)))  short short8;
typedef __attribute__((ext_vector_type(4)))  float f32x4;
typedef __attribute__((ext_vector_type(16))) float f32x16;

__device__ __forceinline__ unsigned short f2bf(float f) {
    union { float f; uint32_t u; } v; v.f = f;
    uint32_t u = v.u;
    uint32_t r = (u + 0x7FFFu + ((u >> 16) & 1u)) >> 16;   // RNE
    return (unsigned short)r;
}

#define GLL(src, dst) __builtin_amdgcn_global_load_lds(                      \
        (__attribute__((address_space(1))) void*)(src),                      \
        (__attribute__((address_space(3))) void*)(dst), 16, 0, 0)

// ---------------- fp32 -> bf16 convert + PRE-SWIZZLE (4 weight matrices) ----------------
// W_sw[j][kb*8..] = W[j][kbs*8..], kbs = (kb&~7)|((kb^j)&7)
__global__ void cvt_w(const float* __restrict__ wq, const float* __restrict__ wk,
                      const float* __restrict__ wv, const float* __restrict__ wo,
                      unsigned short* __restrict__ dst)
{
    int i = blockIdx.x * 256 + threadIdx.x;      // 16B-block id: 4 * 1024 * 128
    int a = i >> 17;
    int r = i & 131071;
    int j = r >> 7, kb = r & 127;
    int kbs = (kb & ~7) | ((kb ^ j) & 7);
    const float* s = (a == 0 ? wq : a == 1 ? wk : a == 2 ? wv : wo) + (size_t)j * 1024 + kbs * 8;
    float4 f0 = *(const float4*)(s);
    float4 f1 = *(const float4*)(s + 4);
    union { uint32_t u[4]; short8 s8; } c;
    asm("v_cvt_pk_bf16_f32 %0, %1, %2" : "=v"(c.u[0]) : "v"(f0.x), "v"(f0.y));
    asm("v_cvt_pk_bf16_f32 %0, %1, %2" : "=v"(c.u[1]) : "v"(f0.z), "v"(f0.w));
    asm("v_cvt_pk_bf16_f32 %0, %1, %2" : "=v"(c.u[2]) : "v"(f1.x), "v"(f1.y));
    asm("v_cvt_pk_bf16_f32 %0, %1, %2" : "=v"(c.u[3]) : "v"(f1.z), "v"(f1.w));
    *(short8*)(dst + ((size_t)a << 20) + (size_t)j * 1024 + kb * 8) = c.s8;
}

// -------- merged QKV GEMM: serial 2-phase (r17 sync), fp32-A via GLL, consumer-side cvt ----
// A: fp32 staged by 8 GLL/wave-calls into 32KB LDS, LINEAR dest; global SOURCE pre-swizzled
//    per-lane at 16B-unit granularity: LDS(r, u) = A(r, u ^ (r&7)). Consumer reads units
//    (2pb)^(r&7) and (2pb+1)^(r&7) (two b128, 2-way bank alias = free) + 4 cvt_pk -> frag.
// B: pre-swizzled bf16 W via GLL (linear), reads XOR pb^(row&7) — unchanged from r17.
__global__ __launch_bounds__(256) void gemm_qkv(
        const float* __restrict__ Aq, const float* __restrict__ Ak, const float* __restrict__ Av,
        const unsigned short* __restrict__ Wq, const unsigned short* __restrict__ Wk,
        const unsigned short* __restrict__ Wv,
        const float* __restrict__ bq, const float* __restrict__ bk, const float* __restrict__ bv,
        unsigned short* __restrict__ Qo, unsigned short* __restrict__ Ko,
        unsigned short* __restrict__ Vo, const float qscale)
{
    const int orig = blockIdx.z * 512 + blockIdx.y * 8 + blockIdx.x;
    const int wid  = (orig & 7) * 192 + (orig >> 3);   // bijective XCD swizzle
    const int z    = wid >> 9;
    const int rem  = wid & 511;
    const int brow = (rem >> 3) * 128;
    const int bcol = (rem & 7) * 128;

    const float* Af          = (z == 0) ? Aq : (z == 1) ? Ak : Av;
    const unsigned short* Bw = (z == 0) ? Wq : (z == 1) ? Wk : Wv;
    const float* bias        = (z == 0) ? bq : (z == 1) ? bk : bv;

    __shared__ __align__(16) float          lAf[128 * 64];    // 32KB fp32, 16B-unit swizzled
    __shared__ __align__(16) unsigned short lB[128 * 64];     // 16KB bf16 (W pre-swizzled)

    const int tid = threadIdx.x;
    const int w = tid >> 6, l = tid & 63;
    const int wr = (w >> 1) * 64, wc = (w & 1) * 64;
    const int lrow = l & 15;
    const int hi = l >> 4;
    const int sr = l >> 3, scb = l & 7;

    // A staging: wave w owns rows [w*32, w*32+32); GLL j covers rows w*32+j*4..+3.
    // lane l: row r = w*32 + j*4 + (l>>4); linear unit u_lin = l&15;
    // source logical unit = u_lin ^ (r&7)  (pre-swizzled source, linear dest).
    const int arow0 = w * 32 + (l >> 4);               // + j*4 per call
    const int aulin = l & 15;
    // B staging (r17): wave chunks of 8 rows, 16B per lane
    f32x4 acc[4][4] = {};

    for (int k0 = 0; k0 < 1024; k0 += 64) {
        // B: 4 GLLs (bf16 W, linear dest, pre-swizzled in global)
#pragma unroll
        for (int i = 0; i < 4; ++i) {
            const int chunk = w * 4 + i;
            const int r = chunk * 8 + sr;
            GLL(Bw + (size_t)(bcol + r) * 1024 + k0 + scb * 8, lB + chunk * 512);
        }
        // A: 8 GLLs (fp32, linear dest, per-lane pre-swizzled source)
#pragma unroll
        for (int j = 0; j < 8; ++j) {
            const int r = arow0 + j * 4;
            const float* ga = Af + (size_t)(brow + r) * 1024 + k0 + ((aulin ^ (r & 7)) << 2);
            GLL(ga, lAf + (size_t)(w * 32 + j * 4) * 64);
        }
        asm volatile("s_waitcnt vmcnt(0)" ::: "memory");
        __syncthreads();
#pragma unroll
        for (int kk = 0; kk < 2; ++kk) {
            short8 af[4], bf[4];
#pragma unroll
            for (int m = 0; m < 4; ++m) {
                const int row = wr + m * 16 + lrow;
                const int pb = kk * 4 + hi;
                const int u0 = (2 * pb) ^ (row & 7);
                const int u1 = (2 * pb + 1) ^ (row & 7);
                f32x4 lo = *(const f32x4*)((const char*)lAf + row * 256 + u0 * 16);
                f32x4 hf = *(const f32x4*)((const char*)lAf + row * 256 + u1 * 16);
                union { uint32_t u[4]; short8 s8; } c;
                asm("v_cvt_pk_bf16_f32 %0, %1, %2" : "=v"(c.u[0]) : "v"(lo[0]), "v"(lo[1]));
                asm("v_cvt_pk_bf16_f32 %0, %1, %2" : "=v"(c.u[1]) : "v"(lo[2]), "v"(lo[3]));
                asm("v_cvt_pk_bf16_f32 %0, %1, %2" : "=v"(c.u[2]) : "v"(hf[0]), "v"(hf[1]));
                asm("v_cvt_pk_bf16_f32 %0, %1, %2" : "=v"(c.u[3]) : "v"(hf[2]), "v"(hf[3]));
                af[m] = c.s8;
            }
#pragma unroll
            for (int n = 0; n < 4; ++n) {
                const int row = wc + n * 16 + lrow;
                const int pb = (kk * 4 + hi) ^ (row & 7);
                bf[n] = *(const short8*)((const char*)lB + row * 128 + (pb << 4));
            }
            __builtin_amdgcn_s_setprio(1);
#pragma unroll
            for (int m = 0; m < 4; ++m)
#pragma unroll
                for (int n = 0; n < 4; ++n)
                    acc[m][n] = __builtin_amdgcn_mfma_f32_16x16x32_bf16(af[m], bf[n], acc[m][n], 0, 0, 0);
            __builtin_amdgcn_s_setprio(0);
        }
        __syncthreads();
    }

    const float ascale = (z == 0) ? qscale : 1.0f;
#pragma unroll
    for (int m = 0; m < 4; ++m) {
#pragma unroll
        for (int n = 0; n < 4; ++n) {
            const int i0 = brow + wr + m * 16 + hi * 4;
            const int j  = bcol + wc + n * 16 + lrow;
            const float bj = bias[j];
            const int hh = j >> 6, d = j & 63;
            if (z < 2) {
                unsigned short* Cb = (z == 0) ? Qo : Ko;
#pragma unroll
                for (int t = 0; t < 4; ++t) {
                    const int i = i0 + t;
                    const int b = i >> 11, s = i & 2047;
                    Cb[(((size_t)(b * NH + hh) * SS) + s) * DKK + d] = f2bf((acc[m][n][t] + bj) * ascale);
                }
            } else {   // V^T
                const int b = i0 >> 11, s0 = i0 & 2047;
                ushort4 pk;
                pk.x = f2bf(acc[m][n][0] + bj);
                pk.y = f2bf(acc[m][n][1] + bj);
                pk.z = f2bf(acc[m][n][2] + bj);
                pk.w = f2bf(acc[m][n][3] + bj);
                *(ushort4*)(Vo + (((size_t)(b * NH + hh) * DKK) + d) * SS + s0) = pk;
            }
        }
    }
}

// ---------------- final projection GEMM: bf16 A reg-staged swizzled, depth-2, fp32 out ------
__global__ __launch_bounds__(256) void gemm_out(
        const unsigned short* __restrict__ A,
        const unsigned short* __restrict__ Bw,
        const float* __restrict__ bias,
        float* __restrict__ Cout)
{
    const int orig = blockIdx.y * 8 + blockIdx.x;
    const int wid  = (orig & 7) * 64 + (orig >> 3);
    const int brow = (wid >> 3) * 128;
    const int bcol = (wid & 7) * 128;

    __shared__ __align__(16) unsigned short lA[128 * 64];
    __shared__ __align__(16) unsigned short lB[2][128 * 64];

    const int tid = threadIdx.x;
    const int w = tid >> 6, l = tid & 63;
    const int wr = (w >> 1) * 64, wc = (w & 1) * 64;
    const int lrow = l & 15;
    const int hi = l >> 4;
    const int sr = l >> 3, scb = l & 7;

    const unsigned short* aga[4];
    const unsigned short* bga[4];
    int awb[4], lbo[4];
#pragma unroll
    for (int i = 0; i < 4; ++i) {
        const int chunk = w * 4 + i;
        const int r = chunk * 8 + sr;
        aga[i] = A  + (size_t)(brow + r) * 1024 + scb * 8;
        bga[i] = Bw + (size_t)(bcol + r) * 1024 + scb * 8;
        awb[i] = chunk * 1024 + sr * 128 + ((scb ^ sr) << 4);
        lbo[i] = chunk * 512;
    }

    short8 aX[4], aY[4];
    f32x4 acc[4][4] = {};

#pragma unroll
    for (int i = 0; i < 4; ++i) GLL(bga[i], lB[0] + lbo[i]);
#pragma unroll
    for (int i = 0; i < 4; ++i) aX[i] = *(const short8*)(aga[i]);
#pragma unroll
    for (int i = 0; i < 4; ++i) aY[i] = *(const short8*)(aga[i] + 64);

#define OUT_WR(CUR)                                                     \
    _Pragma("unroll")                                                   \
    for (int i = 0; i < 4; ++i)                                         \
        *(short8*)((char*)lA + awb[i]) = CUR[i];

#define OUT_MFMA(LB)                                                                              \
    {                                                                                             \
        const unsigned short* lb = (LB);                                                          \
        __builtin_amdgcn_s_setprio(1);                                                            \
        _Pragma("unroll")                                                                         \
        for (int kk = 0; kk < 2; ++kk) {                                                          \
            short8 af[4], bf[4];                                                                  \
            _Pragma("unroll")                                                                     \
            for (int m = 0; m < 4; ++m) {                                                         \
                const int row = wr + m * 16 + lrow;                                               \
                const int pb = (kk * 4 + hi) ^ (row & 7);                                         \
                af[m] = *(const short8*)((const char*)lA + row * 128 + (pb << 4));                \
            }                                                                                     \
            _Pragma("unroll")                                                                     \
            for (int n = 0; n < 4; ++n) {                                                         \
                const int row = wc + n * 16 + lrow;                                               \
                const int pb = (kk * 4 + hi) ^ (row & 7);                                         \
                bf[n] = *(const short8*)((const char*)lb + row * 128 + (pb << 4));                \
            }                                                                                     \
            _Pragma("unroll")                                                                     \
            for (int m = 0; m < 4; ++m)                                                           \
                _Pragma("unroll")                                                                 \
                for (int n = 0; n < 4; ++n)                                                       \
                    acc[m][n] = __builtin_amdgcn_mfma_f32_16x16x32_bf16(af[m], bf[n], acc[m][n], 0, 0, 0); \
        }                                                                                         \
        __builtin_amdgcn_s_setprio(0);                                                            \
    }

    for (int t = 0; t < 14; t += 2) {
        OUT_WR(aX);
        {
            const int ko = (t + 2) * 64;
#pragma unroll
            for (int i = 0; i < 4; ++i) aX[i] = *(const short8*)(aga[i] + ko);
            const int kb = (t + 1) * 64;
#pragma unroll
            for (int i = 0; i < 4; ++i) GLL(bga[i] + kb, lB[1] + lbo[i]);
        }
        asm volatile("s_waitcnt vmcnt(8) lgkmcnt(0)" ::: "memory");
        __builtin_amdgcn_s_barrier();
        OUT_MFMA(lB[0]);
        asm volatile("" ::: "memory");
        __builtin_amdgcn_s_barrier();

        OUT_WR(aY);
        {
            const int ko = (t + 3) * 64;
#pragma unroll
            for (int i = 0; i < 4; ++i) aY[i] = *(const short8*)(aga[i] + ko);
            const int kb = (t + 2) * 64;
#pragma unroll
            for (int i = 0; i < 4; ++i) GLL(bga[i] + kb, lB[0] + lbo[i]);
        }
        asm volatile("s_waitcnt vmcnt(8) lgkmcnt(0)" ::: "memory");
        __builtin_amdgcn_s_barrier();
        OUT_MFMA(lB[1]);
        asm volatile("" ::: "memory");
        __builtin_amdgcn_s_barrier();
    }
    OUT_WR(aX);
#pragma unroll
    for (int i = 0; i < 4; ++i) GLL(bga[i] + 15 * 64, lB[1] + lbo[i]);
    asm volatile("s_waitcnt vmcnt(4) lgkmcnt(0)" ::: "memory");
    __builtin_amdgcn_s_barrier();
    OUT_MFMA(lB[0]);
    asm volatile("" ::: "memory");
    __builtin_amdgcn_s_barrier();
    OUT_WR(aY);
    asm volatile("s_waitcnt vmcnt(0) lgkmcnt(0)" ::: "memory");
    __builtin_amdgcn_s_barrier();
    OUT_MFMA(lB[1]);

#pragma unroll
    for (int m = 0; m < 4; ++m) {
#pragma unroll
        for (int n = 0; n < 4; ++n) {
            const int i0 = brow + wr + m * 16 + (l >> 4) * 4;
            const int j  = bcol + wc + n * 16 + lrow;
            const float bj = bias[j];
#pragma unroll
            for (int t = 0; t < 4; ++t)
                Cout[(size_t)(i0 + t) * DM + j] = acc[m][n][t] + bj;
        }
    }
#undef OUT_WR
#undef OUT_MFMA
}

// ---------------- causal flash attention (round-7, unchanged) ----------------
__global__ __launch_bounds__(256) void attn_kernel(
        const unsigned short* __restrict__ Q,
        const unsigned short* __restrict__ K,
        const unsigned short* __restrict__ Vt,
        unsigned short* __restrict__ AO)
{
    const int flat = blockIdx.y * 16 + blockIdx.x;      // grid (16, 64)
    const int r8 = flat & 7, k8 = flat >> 3;
    const int bh = r8 * 8 + (k8 & 7);                   // 8 heads per XCD-residue (L2 share)
    const int qchunk = 15 - (k8 >> 3);                  // LPT: long blocks first
    const int tid = threadIdx.x;
    const int w = tid >> 6, l = tid & 63;
    const int ln = l & 31, h = l >> 5;
    const int qb = qchunk * 128;
    const int q0w = qb + w * 32;

    __shared__ __align__(16) char lK[2][4096];
    __shared__ __align__(16) char lV[2][4096];

    const unsigned short* Qp = Q  + ((size_t)bh * SS + q0w) * DKK;
    const unsigned short* Kp = K  + (size_t)bh * SS * DKK;
    const unsigned short* Vp = Vt + (size_t)bh * DKK * SS;

    const int srow = tid >> 3, scb = tid & 7;
    const int swb = srow * 128 + ((scb * 16) ^ ((srow & 7) << 4));
    const unsigned short* ksrc = Kp + srow * DKK + scb * 8;            // + t*2048
    const int vd = (scb < 4) ? srow : (srow + 32);
    const unsigned short* vsrc = Vp + (size_t)vd * SS + (scb & 3) * 8; // + t*32

    int ka[4], va[4];
#pragma unroll
    for (int ks = 0; ks < 4; ++ks)
        ka[ks] = ln * 128 + ((ks * 32 + h * 16) ^ ((ln & 7) << 4));
#pragma unroll
    for (int c = 0; c < 4; ++c)
        va[c] = ln * 128 + ((c * 32 + h * 16) ^ ((ln & 7) << 4));

    short8 qf[4];
#pragma unroll
    for (int ks = 0; ks < 4; ++ks)
        qf[ks] = *(const short8*)(Qp + (size_t)ln * DKK + ks * 16 + h * 8);

    f32x16 o0 = {}, o1 = {};
    float lsum = 0.f;

    const int Tc = qb / 32;
    const int NT = Tc + 4;

    auto compute = [&](int t, int buf) {
        const char* kb = lK[buf];
        const char* vb = lV[buf];
        short8 kf[4];
#pragma unroll
        for (int ks = 0; ks < 4; ++ks) kf[ks] = *(const short8*)(kb + ka[ks]);

        f32x16 s = {};
        __builtin_amdgcn_s_setprio(1);
#pragma unroll
        for (int ks = 0; ks < 4; ++ks)
            s = __builtin_amdgcn_mfma_f32_32x32x16_bf16(kf[ks], qf[ks], s, 0, 0, 0);
        __builtin_amdgcn_s_setprio(0);

        const bool diag = (t == Tc + w);
#pragma unroll
        for (int r = 0; r < 16; ++r) {
            float e;
            asm("v_exp_f32 %0, %1" : "=v"(e) : "v"(s[r]));   // 2^s (Q pre-scaled)
            if (diag) {
                const int crow = (r & 3) + 8 * (r >> 2) + 4 * h;
                e = (crow > ln) ? 0.f : e;
            }
            s[r] = e;
            lsum += e;
        }

        uint32_t pk[8];
#pragma unroll
        for (int i = 0; i < 8; ++i) {
            uint32_t d;
            asm("v_cvt_pk_bf16_f32 %0, %1, %2" : "=v"(d) : "v"(s[2 * i]), "v"(s[2 * i + 1]));
            pk[i] = d;
        }
        asm("v_permlane32_swap_b32 %0, %1" : "+v"(pk[0]), "+v"(pk[2]));
        asm("v_permlane32_swap_b32 %0, %1" : "+v"(pk[1]), "+v"(pk[3]));
        asm("v_permlane32_swap_b32 %0, %1" : "+v"(pk[4]), "+v"(pk[6]));
        asm("v_permlane32_swap_b32 %0, %1" : "+v"(pk[5]), "+v"(pk[7]));

        union Ux { uint32_t u[4]; short8 s8; } pa0, pa1;
        pa0.u[0] = pk[0]; pa0.u[1] = pk[1]; pa0.u[2] = pk[2]; pa0.u[3] = pk[3];
        pa1.u[0] = pk[4]; pa1.u[1] = pk[5]; pa1.u[2] = pk[6]; pa1.u[3] = pk[7];

        short8 vf00 = *(const short8*)(vb + va[0]);
        short8 vf10 = *(const short8*)(vb + va[1]);
        short8 vf01 = *(const short8*)(vb + va[2]);
        short8 vf11 = *(const short8*)(vb + va[3]);

        __builtin_amdgcn_s_setprio(1);
        o0 = __builtin_amdgcn_mfma_f32_32x32x16_bf16(pa0.s8, vf00, o0, 0, 0, 0);
        o0 = __builtin_amdgcn_mfma_f32_32x32x16_bf16(pa1.s8, vf10, o0, 0, 0, 0);
        o1 = __builtin_amdgcn_mfma_f32_32x32x16_bf16(pa0.s8, vf01, o1, 0, 0, 0);
        o1 = __builtin_amdgcn_mfma_f32_32x32x16_bf16(pa1.s8, vf11, o1, 0, 0, 0);
        __builtin_amdgcn_s_setprio(0);
    };

    short8 kA = *(const short8*)(ksrc);
    short8 vA = *(const short8*)(vsrc);
    *(short8*)(&lK[0][swb]) = kA;
    *(short8*)(&lV[0][swb]) = vA;
    kA = *(const short8*)(ksrc + 2048);
    vA = *(const short8*)(vsrc + 32);
    short8 kB = {}, vB = {};
    __syncthreads();

    int t = 0, buf = 0;
    for (;;) {
        if (t + 2 < NT) {
            kB = *(const short8*)(ksrc + (size_t)(t + 2) * 2048);
            vB = *(const short8*)(vsrc + (size_t)(t + 2) * 32);
        }
        if (t <= Tc + w) compute(t, buf);
        if (t + 1 < NT) {
            *(short8*)(&lK[buf ^ 1][swb]) = kA;
            *(short8*)(&lV[buf ^ 1][swb]) = vA;
        }
        __syncthreads();
        buf ^= 1;
        if (++t == NT) break;

        if (t + 2 < NT) {
            kA = *(const short8*)(ksrc + (size_t)(t + 2) * 2048);
            vA = *(const short8*)(vsrc + (size_t)(t + 2) * 32);
        }
        if (t <= Tc + w) compute(t, buf);
        if (t + 1 < NT) {
            *(short8*)(&lK[buf ^ 1][swb]) = kB;
            *(short8*)(&lV[buf ^ 1][swb]) = vB;
        }
        __syncthreads();
        buf ^= 1;
        if (++t == NT) break;
    }

    lsum += __shfl_xor(lsum, 32, 64);
    const float rcp = 1.0f / lsum;

    const int bb = bh >> 4, hh = bh & 15;
#pragma unroll
    for (int r = 0; r < 16; ++r) {
        const int crow = (r & 3) + 8 * (r >> 2) + 4 * h;
        const float rl = __shfl(rcp, crow, 64);
        const size_t row = (size_t)(bb * SS + q0w + crow) * DM + hh * DKK;
        AO[row + ln]      = f2bf(o0[r] * rl);
        AO[row + 32 + ln] = f2bf(o1[r] * rl);
    }
}

extern "C" void kernel_launch(void* const* d_in, const int* in_sizes, int n_in,
                              void* d_out, int out_size, void* d_ws, size_t ws_size,
                              hipStream_t stream)
{
    const float* query  = (const float*)d_in[0];
    const float* key_in = (const float*)d_in[1];
    const float* value  = (const float*)d_in[2];
    const float* Wq = (const float*)d_in[3];
    const float* bq = (const float*)d_in[4];
    const float* Wk = (const float*)d_in[5];
    const float* bk = (const float*)d_in[6];
    const float* Wv = (const float*)d_in[7];
    const float* bv = (const float*)d_in[8];
    const float* Wo = (const float*)d_in[9];
    const float* bo = (const float*)d_in[10];

    const size_t NACT = (size_t)BB * SS * DM;   // 8388608
    const size_t NWT  = (size_t)DM * DM;        // 1048576

    unsigned short* ws  = (unsigned short*)d_ws;
    unsigned short* wqb = ws;
    unsigned short* wkb = wqb + NWT;
    unsigned short* wvb = wkb + NWT;
    unsigned short* wob = wvb + NWT;
    unsigned short* Qb  = wob + NWT;
    unsigned short* Kb  = Qb + NACT;
    unsigned short* Vtb = Kb + NACT;
    unsigned short* AOb = Vtb + NACT;

    cvt_w<<<2048, 256, 0, stream>>>(Wq, Wk, Wv, Wo, ws);

    const float QSCALE = 0.125f * 1.44269504088896f;   // 1/sqrt(64) * log2(e)
    dim3 gq(8, 64, 3);   // 1536 blocks
    gemm_qkv<<<gq, 256, 0, stream>>>(query, key_in, value, wqb, wkb, wvb,
                                     bq, bk, bv, Qb, Kb, Vtb, QSCALE);

    attn_kernel<<<dim3(16, 64), 256, 0, stream>>>(Qb, Kb, Vtb, AOb);

    dim3 gg(DM / 128, (BB * SS) / 128);   // (8, 64)
    gemm_out<<<gg, 256, 0, stream>>>(AOb, wob, bo, (float*)d_out);
}

// Round 22
// 160.368 us; speedup vs baseline: 1.2508x; 1.1014x over previous
//
#include <hip/hip_runtime.h>
#include <hip/hip_bf16.h>
#include <cstdint>

#define DM   1024
#define NH   16
#define DKK  64
#define BB   4
#define SS   2048

typedef __attribute__((ext_vector_type(8)))  short short8;
typedef __attribute__((ext_vector_type(4)))  float f32x4;
typedef __attribute__((ext_vector_type(16))) float f32x16;

__device__ __forceinline__ unsigned short f2bf(float f) {
    union { float f; uint32_t u; } v; v.f = f;
    uint32_t u = v.u;
    uint32_t r = (u + 0x7FFFu + ((u >> 16) & 1u)) >> 16;   // RNE
    return (unsigned short)r;
}

#define GLL(src, dst) __builtin_amdgcn_global_load_lds(                      \
        (__attribute__((address_space(1))) void*)(src),                      \
        (__attribute__((address_space(3))) void*)(dst), 16, 0, 0)

// ---------------- fp32 -> bf16 convert + PRE-SWIZZLE (4 weight matrices) ----------------
// W_sw[j][kb*8..] = W[j][kbs*8..], kbs = (kb&~7)|((kb^j)&7)
__global__ void cvt_w(const float* __restrict__ wq, const float* __restrict__ wk,
                      const float* __restrict__ wv, const float* __restrict__ wo,
                      unsigned short* __restrict__ dst)
{
    int i = blockIdx.x * 256 + threadIdx.x;      // 16B-block id: 4 * 1024 * 128
    int a = i >> 17;
    int r = i & 131071;
    int j = r >> 7, kb = r & 127;
    int kbs = (kb & ~7) | ((kb ^ j) & 7);
    const float* s = (a == 0 ? wq : a == 1 ? wk : a == 2 ? wv : wo) + (size_t)j * 1024 + kbs * 8;
    float4 f0 = *(const float4*)(s);
    float4 f1 = *(const float4*)(s + 4);
    union { uint32_t u[4]; short8 s8; } c;
    asm("v_cvt_pk_bf16_f32 %0, %1, %2" : "=v"(c.u[0]) : "v"(f0.x), "v"(f0.y));
    asm("v_cvt_pk_bf16_f32 %0, %1, %2" : "=v"(c.u[1]) : "v"(f0.z), "v"(f0.w));
    asm("v_cvt_pk_bf16_f32 %0, %1, %2" : "=v"(c.u[2]) : "v"(f1.x), "v"(f1.y));
    asm("v_cvt_pk_bf16_f32 %0, %1, %2" : "=v"(c.u[3]) : "v"(f1.z), "v"(f1.w));
    *(short8*)(dst + ((size_t)a << 20) + (size_t)j * 1024 + kb * 8) = c.s8;
}

// ---------------- merged QKV GEMM: round-7 serial 2-phase, fused fp32-A cvt ----------------
// 32 KB LDS -> ~5 blocks/CU; latency hidden by cross-block TLP (m114), no hand pipeline.
// A: fp32 -> regs -> cvt_pk -> XOR-swizzled lA write. B: pre-swizzled W via GLL (linear).
// Reads XOR back: pb = (kk*4+hi) ^ (row&7).
__global__ void gemm_qkv(
        const float* __restrict__ Aq, const float* __restrict__ Ak, const float* __restrict__ Av,
        const unsigned short* __restrict__ Wq, const unsigned short* __restrict__ Wk,
        const unsigned short* __restrict__ Wv,
        const float* __restrict__ bq, const float* __restrict__ bk, const float* __restrict__ bv,
        unsigned short* __restrict__ Qo, unsigned short* __restrict__ Ko,
        unsigned short* __restrict__ Vo, const float qscale)
{
    // bijective XCD swizzle: 1536 blocks, 192 contiguous wids/XCD (A-panel + W reuse in L2)
    const int orig = blockIdx.z * 512 + blockIdx.y * 8 + blockIdx.x;
    const int wid  = (orig & 7) * 192 + (orig >> 3);
    const int z    = wid >> 9;
    const int rem  = wid & 511;
    const int brow = (rem >> 3) * 128;
    const int bcol = (rem & 7) * 128;

    const float* A           = (z == 0) ? Aq : (z == 1) ? Ak : Av;
    const unsigned short* Bw = (z == 0) ? Wq : (z == 1) ? Wk : Wv;
    const float* bias        = (z == 0) ? bq : (z == 1) ? bk : bv;

    __shared__ __align__(16) unsigned short lA[128 * 64];
    __shared__ __align__(16) unsigned short lB[128 * 64];
    const int tid = threadIdx.x;
    const int w = tid >> 6, l = tid & 63;
    const int wr = (w >> 1) * 64, wc = (w & 1) * 64;
    const int lrow = l & 15;
    const int hi = l >> 4;
    const int sr = l >> 3;          // row within 8-row chunk (= row&7)
    const int scb = l & 7;          // 16B-block col
    f32x4 acc[4][4] = {};

    for (int k0 = 0; k0 < 1024; k0 += 64) {
        // B: async global->LDS (pre-swizzled bf16 weights, linear dest)
#pragma unroll
        for (int i = 0; i < 4; ++i) {
            const int chunk = w * 4 + i;
            const int r = chunk * 8 + sr;
            const unsigned short* gb = Bw + (size_t)(bcol + r) * 1024 + k0 + scb * 8;
            GLL(gb, lB + chunk * 512);
        }
        // A: reg-staged fp32 -> bf16 -> XOR-swizzled LDS write
#pragma unroll
        for (int i = 0; i < 4; ++i) {
            const int chunk = w * 4 + i;
            const int r = chunk * 8 + sr;
            const float* ga = A + (size_t)(brow + r) * 1024 + k0 + scb * 8;
            float4 f0 = *(const float4*)(ga);
            float4 f1 = *(const float4*)(ga + 4);
            union { uint32_t u[4]; short8 s8; } c;
            asm("v_cvt_pk_bf16_f32 %0, %1, %2" : "=v"(c.u[0]) : "v"(f0.x), "v"(f0.y));
            asm("v_cvt_pk_bf16_f32 %0, %1, %2" : "=v"(c.u[1]) : "v"(f0.z), "v"(f0.w));
            asm("v_cvt_pk_bf16_f32 %0, %1, %2" : "=v"(c.u[2]) : "v"(f1.x), "v"(f1.y));
            asm("v_cvt_pk_bf16_f32 %0, %1, %2" : "=v"(c.u[3]) : "v"(f1.z), "v"(f1.w));
            *(short8*)((char*)lA + chunk * 1024 + sr * 128 + ((scb ^ sr) << 4)) = c.s8;
        }
        asm volatile("s_waitcnt vmcnt(0)" ::: "memory");
        __syncthreads();
#pragma unroll
        for (int kk = 0; kk < 2; ++kk) {
            short8 af[4], bf[4];
#pragma unroll
            for (int m = 0; m < 4; ++m) {
                const int row = wr + m * 16 + lrow;
                const int pb = (kk * 4 + hi) ^ (row & 7);
                af[m] = *(const short8*)((const char*)lA + row * 128 + (pb << 4));
            }
#pragma unroll
            for (int n = 0; n < 4; ++n) {
                const int row = wc + n * 16 + lrow;
                const int pb = (kk * 4 + hi) ^ (row & 7);
                bf[n] = *(const short8*)((const char*)lB + row * 128 + (pb << 4));
            }
#pragma unroll
            for (int m = 0; m < 4; ++m)
#pragma unroll
                for (int n = 0; n < 4; ++n)
                    acc[m][n] = __builtin_amdgcn_mfma_f32_16x16x32_bf16(af[m], bf[n], acc[m][n], 0, 0, 0);
        }
        __syncthreads();
    }

    const float ascale = (z == 0) ? qscale : 1.0f;
#pragma unroll
    for (int m = 0; m < 4; ++m) {
#pragma unroll
        for (int n = 0; n < 4; ++n) {
            const int i0 = brow + wr + m * 16 + hi * 4;
            const int j  = bcol + wc + n * 16 + lrow;
            const float bj = bias[j];
            const int hh = j >> 6, d = j & 63;
            if (z < 2) {
                unsigned short* Cb = (z == 0) ? Qo : Ko;
#pragma unroll
                for (int t = 0; t < 4; ++t) {
                    const int i = i0 + t;
                    const int b = i >> 11, s = i & 2047;
                    Cb[(((size_t)(b * NH + hh) * SS) + s) * DKK + d] = f2bf((acc[m][n][t] + bj) * ascale);
                }
            } else {   // V^T
                const int b = i0 >> 11, s0 = i0 & 2047;
                ushort4 pk;
                pk.x = f2bf(acc[m][n][0] + bj);
                pk.y = f2bf(acc[m][n][1] + bj);
                pk.z = f2bf(acc[m][n][2] + bj);
                pk.w = f2bf(acc[m][n][3] + bj);
                *(ushort4*)(Vo + (((size_t)(b * NH + hh) * DKK) + d) * SS + s0) = pk;
            }
        }
    }
}

// ---------------- final projection GEMM: bf16 A reg-staged swizzled, depth-2, fp32 out ------
__global__ __launch_bounds__(256) void gemm_out(
        const unsigned short* __restrict__ A,
        const unsigned short* __restrict__ Bw,
        const float* __restrict__ bias,
        float* __restrict__ Cout)
{
    const int orig = blockIdx.y * 8 + blockIdx.x;
    const int wid  = (orig & 7) * 64 + (orig >> 3);
    const int brow = (wid >> 3) * 128;
    const int bcol = (wid & 7) * 128;

    __shared__ __align__(16) unsigned short lA[128 * 64];
    __shared__ __align__(16) unsigned short lB[2][128 * 64];

    const int tid = threadIdx.x;
    const int w = tid >> 6, l = tid & 63;
    const int wr = (w >> 1) * 64, wc = (w & 1) * 64;
    const int lrow = l & 15;
    const int hi = l >> 4;
    const int sr = l >> 3, scb = l & 7;

    const unsigned short* aga[4];
    const unsigned short* bga[4];
    int awb[4], lbo[4];
#pragma unroll
    for (int i = 0; i < 4; ++i) {
        const int chunk = w * 4 + i;
        const int r = chunk * 8 + sr;
        aga[i] = A  + (size_t)(brow + r) * 1024 + scb * 8;
        bga[i] = Bw + (size_t)(bcol + r) * 1024 + scb * 8;
        awb[i] = chunk * 1024 + sr * 128 + ((scb ^ sr) << 4);
        lbo[i] = chunk * 512;
    }

    short8 aX[4], aY[4];
    f32x4 acc[4][4] = {};

#pragma unroll
    for (int i = 0; i < 4; ++i) GLL(bga[i], lB[0] + lbo[i]);
#pragma unroll
    for (int i = 0; i < 4; ++i) aX[i] = *(const short8*)(aga[i]);
#pragma unroll
    for (int i = 0; i < 4; ++i) aY[i] = *(const short8*)(aga[i] + 64);

#define OUT_WR(CUR)                                                     \
    _Pragma("unroll")                                                   \
    for (int i = 0; i < 4; ++i)                                         \
        *(short8*)((char*)lA + awb[i]) = CUR[i];

#define OUT_MFMA(LB)                                                                              \
    {                                                                                             \
        const unsigned short* lb = (LB);                                                          \
        __builtin_amdgcn_s_setprio(1);                                                            \
        _Pragma("unroll")                                                                         \
        for (int kk = 0; kk < 2; ++kk) {                                                          \
            short8 af[4], bf[4];                                                                  \
            _Pragma("unroll")                                                                     \
            for (int m = 0; m < 4; ++m) {                                                         \
                const int row = wr + m * 16 + lrow;                                               \
                const int pb = (kk * 4 + hi) ^ (row & 7);                                         \
                af[m] = *(const short8*)((const char*)lA + row * 128 + (pb << 4));                \
            }                                                                                     \
            _Pragma("unroll")                                                                     \
            for (int n = 0; n < 4; ++n) {                                                         \
                const int row = wc + n * 16 + lrow;                                               \
                const int pb = (kk * 4 + hi) ^ (row & 7);                                         \
                bf[n] = *(const short8*)((const char*)lb + row * 128 + (pb << 4));                \
            }                                                                                     \
            _Pragma("unroll")                                                                     \
            for (int m = 0; m < 4; ++m)                                                           \
                _Pragma("unroll")                                                                 \
                for (int n = 0; n < 4; ++n)                                                       \
                    acc[m][n] = __builtin_amdgcn_mfma_f32_16x16x32_bf16(af[m], bf[n], acc[m][n], 0, 0, 0); \
        }                                                                                         \
        __builtin_amdgcn_s_setprio(0);                                                            \
    }

    for (int t = 0; t < 14; t += 2) {
        OUT_WR(aX);
        {
            const int ko = (t + 2) * 64;
#pragma unroll
            for (int i = 0; i < 4; ++i) aX[i] = *(const short8*)(aga[i] + ko);
            const int kb = (t + 1) * 64;
#pragma unroll
            for (int i = 0; i < 4; ++i) GLL(bga[i] + kb, lB[1] + lbo[i]);
        }
        asm volatile("s_waitcnt vmcnt(8) lgkmcnt(0)" ::: "memory");
        __builtin_amdgcn_s_barrier();
        OUT_MFMA(lB[0]);
        asm volatile("" ::: "memory");
        __builtin_amdgcn_s_barrier();

        OUT_WR(aY);
        {
            const int ko = (t + 3) * 64;
#pragma unroll
            for (int i = 0; i < 4; ++i) aY[i] = *(const short8*)(aga[i] + ko);
            const int kb = (t + 2) * 64;
#pragma unroll
            for (int i = 0; i < 4; ++i) GLL(bga[i] + kb, lB[0] + lbo[i]);
        }
        asm volatile("s_waitcnt vmcnt(8) lgkmcnt(0)" ::: "memory");
        __builtin_amdgcn_s_barrier();
        OUT_MFMA(lB[1]);
        asm volatile("" ::: "memory");
        __builtin_amdgcn_s_barrier();
    }
    OUT_WR(aX);
#pragma unroll
    for (int i = 0; i < 4; ++i) GLL(bga[i] + 15 * 64, lB[1] + lbo[i]);
    asm volatile("s_waitcnt vmcnt(4) lgkmcnt(0)" ::: "memory");
    __builtin_amdgcn_s_barrier();
    OUT_MFMA(lB[0]);
    asm volatile("" ::: "memory");
    __builtin_amdgcn_s_barrier();
    OUT_WR(aY);
    asm volatile("s_waitcnt vmcnt(0) lgkmcnt(0)" ::: "memory");
    __builtin_amdgcn_s_barrier();
    OUT_MFMA(lB[1]);

#pragma unroll
    for (int m = 0; m < 4; ++m) {
#pragma unroll
        for (int n = 0; n < 4; ++n) {
            const int i0 = brow + wr + m * 16 + (l >> 4) * 4;
            const int j  = bcol + wc + n * 16 + lrow;
            const float bj = bias[j];
#pragma unroll
            for (int t = 0; t < 4; ++t)
                Cout[(size_t)(i0 + t) * DM + j] = acc[m][n][t] + bj;
        }
    }
#undef OUT_WR
#undef OUT_MFMA
}

// ---------------- causal flash attention (round-7, unchanged) ----------------
__global__ __launch_bounds__(256) void attn_kernel(
        const unsigned short* __restrict__ Q,
        const unsigned short* __restrict__ K,
        const unsigned short* __restrict__ Vt,
        unsigned short* __restrict__ AO)
{
    const int flat = blockIdx.y * 16 + blockIdx.x;      // grid (16, 64)
    const int r8 = flat & 7, k8 = flat >> 3;
    const int bh = r8 * 8 + (k8 & 7);                   // 8 heads per XCD-residue (L2 share)
    const int qchunk = 15 - (k8 >> 3);                  // LPT: long blocks first
    const int tid = threadIdx.x;
    const int w = tid >> 6, l = tid & 63;
    const int ln = l & 31, h = l >> 5;
    const int qb = qchunk * 128;
    const int q0w = qb + w * 32;

    __shared__ __align__(16) char lK[2][4096];
    __shared__ __align__(16) char lV[2][4096];

    const unsigned short* Qp = Q  + ((size_t)bh * SS + q0w) * DKK;
    const unsigned short* Kp = K  + (size_t)bh * SS * DKK;
    const unsigned short* Vp = Vt + (size_t)bh * DKK * SS;

    const int srow = tid >> 3, scb = tid & 7;
    const int swb = srow * 128 + ((scb * 16) ^ ((srow & 7) << 4));
    const unsigned short* ksrc = Kp + srow * DKK + scb * 8;            // + t*2048
    const int vd = (scb < 4) ? srow : (srow + 32);
    const unsigned short* vsrc = Vp + (size_t)vd * SS + (scb & 3) * 8; // + t*32

    int ka[4], va[4];
#pragma unroll
    for (int ks = 0; ks < 4; ++ks)
        ka[ks] = ln * 128 + ((ks * 32 + h * 16) ^ ((ln & 7) << 4));
#pragma unroll
    for (int c = 0; c < 4; ++c)
        va[c] = ln * 128 + ((c * 32 + h * 16) ^ ((ln & 7) << 4));

    short8 qf[4];
#pragma unroll
    for (int ks = 0; ks < 4; ++ks)
        qf[ks] = *(const short8*)(Qp + (size_t)ln * DKK + ks * 16 + h * 8);

    f32x16 o0 = {}, o1 = {};
    float lsum = 0.f;

    const int Tc = qb / 32;
    const int NT = Tc + 4;

    auto compute = [&](int t, int buf) {
        const char* kb = lK[buf];
        const char* vb = lV[buf];
        short8 kf[4];
#pragma unroll
        for (int ks = 0; ks < 4; ++ks) kf[ks] = *(const short8*)(kb + ka[ks]);

        f32x16 s = {};
        __builtin_amdgcn_s_setprio(1);
#pragma unroll
        for (int ks = 0; ks < 4; ++ks)
            s = __builtin_amdgcn_mfma_f32_32x32x16_bf16(kf[ks], qf[ks], s, 0, 0, 0);
        __builtin_amdgcn_s_setprio(0);

        const bool diag = (t == Tc + w);
#pragma unroll
        for (int r = 0; r < 16; ++r) {
            float e;
            asm("v_exp_f32 %0, %1" : "=v"(e) : "v"(s[r]));   // 2^s (Q pre-scaled)
            if (diag) {
                const int crow = (r & 3) + 8 * (r >> 2) + 4 * h;
                e = (crow > ln) ? 0.f : e;
            }
            s[r] = e;
            lsum += e;
        }

        uint32_t pk[8];
#pragma unroll
        for (int i = 0; i < 8; ++i) {
            uint32_t d;
            asm("v_cvt_pk_bf16_f32 %0, %1, %2" : "=v"(d) : "v"(s[2 * i]), "v"(s[2 * i + 1]));
            pk[i] = d;
        }
        asm("v_permlane32_swap_b32 %0, %1" : "+v"(pk[0]), "+v"(pk[2]));
        asm("v_permlane32_swap_b32 %0, %1" : "+v"(pk[1]), "+v"(pk[3]));
        asm("v_permlane32_swap_b32 %0, %1" : "+v"(pk[4]), "+v"(pk[6]));
        asm("v_permlane32_swap_b32 %0, %1" : "+v"(pk[5]), "+v"(pk[7]));

        union Ux { uint32_t u[4]; short8 s8; } pa0, pa1;
        pa0.u[0] = pk[0]; pa0.u[1] = pk[1]; pa0.u[2] = pk[2]; pa0.u[3] = pk[3];
        pa1.u[0] = pk[4]; pa1.u[1] = pk[5]; pa1.u[2] = pk[6]; pa1.u[3] = pk[7];

        short8 vf00 = *(const short8*)(vb + va[0]);
        short8 vf10 = *(const short8*)(vb + va[1]);
        short8 vf01 = *(const short8*)(vb + va[2]);
        short8 vf11 = *(const short8*)(vb + va[3]);

        __builtin_amdgcn_s_setprio(1);
        o0 = __builtin_amdgcn_mfma_f32_32x32x16_bf16(pa0.s8, vf00, o0, 0, 0, 0);
        o0 = __builtin_amdgcn_mfma_f32_32x32x16_bf16(pa1.s8, vf10, o0, 0, 0, 0);
        o1 = __builtin_amdgcn_mfma_f32_32x32x16_bf16(pa0.s8, vf01, o1, 0, 0, 0);
        o1 = __builtin_amdgcn_mfma_f32_32x32x16_bf16(pa1.s8, vf11, o1, 0, 0, 0);
        __builtin_amdgcn_s_setprio(0);
    };

    short8 kA = *(const short8*)(ksrc);
    short8 vA = *(const short8*)(vsrc);
    *(short8*)(&lK[0][swb]) = kA;
    *(short8*)(&lV[0][swb]) = vA;
    kA = *(const short8*)(ksrc + 2048);
    vA = *(const short8*)(vsrc + 32);
    short8 kB = {}, vB = {};
    __syncthreads();

    int t = 0, buf = 0;
    for (;;) {
        if (t + 2 < NT) {
            kB = *(const short8*)(ksrc + (size_t)(t + 2) * 2048);
            vB = *(const short8*)(vsrc + (size_t)(t + 2) * 32);
        }
        if (t <= Tc + w) compute(t, buf);
        if (t + 1 < NT) {
            *(short8*)(&lK[buf ^ 1][swb]) = kA;
            *(short8*)(&lV[buf ^ 1][swb]) = vA;
        }
        __syncthreads();
        buf ^= 1;
        if (++t == NT) break;

        if (t + 2 < NT) {
            kA = *(const short8*)(ksrc + (size_t)(t + 2) * 2048);
            vA = *(const short8*)(vsrc + (size_t)(t + 2) * 32);
        }
        if (t <= Tc + w) compute(t, buf);
        if (t + 1 < NT) {
            *(short8*)(&lK[buf ^ 1][swb]) = kB;
            *(short8*)(&lV[buf ^ 1][swb]) = vB;
        }
        __syncthreads();
        buf ^= 1;
        if (++t == NT) break;
    }

    lsum += __shfl_xor(lsum, 32, 64);
    const float rcp = 1.0f / lsum;

    const int bb = bh >> 4, hh = bh & 15;
#pragma unroll
    for (int r = 0; r < 16; ++r) {
        const int crow = (r & 3) + 8 * (r >> 2) + 4 * h;
        const float rl = __shfl(rcp, crow, 64);
        const size_t row = (size_t)(bb * SS + q0w + crow) * DM + hh * DKK;
        AO[row + ln]      = f2bf(o0[r] * rl);
        AO[row + 32 + ln] = f2bf(o1[r] * rl);
    }
}

extern "C" void kernel_launch(void* const* d_in, const int* in_sizes, int n_in,
                              void* d_out, int out_size, void* d_ws, size_t ws_size,
                              hipStream_t stream)
{
    const float* query  = (const float*)d_in[0];
    const float* key_in = (const float*)d_in[1];
    const float* value  = (const float*)d_in[2];
    const float* Wq = (const float*)d_in[3];
    const float* bq = (const float*)d_in[4];
    const float* Wk = (const float*)d_in[5];
    const float* bk = (const float*)d_in[6];
    const float* Wv = (const float*)d_in[7];
    const float* bv = (const float*)d_in[8];
    const float* Wo = (const float*)d_in[9];
    const float* bo = (const float*)d_in[10];

    const size_t NACT = (size_t)BB * SS * DM;   // 8388608
    const size_t NWT  = (size_t)DM * DM;        // 1048576

    unsigned short* ws  = (unsigned short*)d_ws;
    unsigned short* wqb = ws;
    unsigned short* wkb = wqb + NWT;
    unsigned short* wvb = wkb + NWT;
    unsigned short* wob = wvb + NWT;
    unsigned short* Qb  = wob + NWT;
    unsigned short* Kb  = Qb + NACT;
    unsigned short* Vtb = Kb + NACT;
    unsigned short* AOb = Vtb + NACT;

    cvt_w<<<2048, 256, 0, stream>>>(Wq, Wk, Wv, Wo, ws);

    const float QSCALE = 0.125f * 1.44269504088896f;   // 1/sqrt(64) * log2(e)
    dim3 gq(8, 64, 3);   // 1536 blocks
    gemm_qkv<<<gq, 256, 0, stream>>>(query, key_in, value, wqb, wkb, wvb,
                                     bq, bk, bv, Qb, Kb, Vtb, QSCALE);

    attn_kernel<<<dim3(16, 64), 256, 0, stream>>>(Qb, Kb, Vtb, AOb);

    dim3 gg(DM / 128, (BB * SS) / 128);   // (8, 64)
    gemm_out<<<gg, 256, 0, stream>>>(AOb, wob, bo, (float*)d_out);
}

// Round 23
// 158.029 us; speedup vs baseline: 1.2693x; 1.0148x over previous
//
#include <hip/hip_runtime.h>
#include <hip/hip_bf16.h>
#include <cstdint>

#define DM   1024
#define NH   16
#define DKK  64
#define BB   4
#define SS   2048

typedef __attribute__((ext_vector_type(8)))  short short8;
typedef __attribute__((ext_vector_type(4)))  float f32x4;
typedef __attribute__((ext_vector_type(16))) float f32x16;

__device__ __forceinline__ unsigned short f2bf(float f) {
    union { float f; uint32_t u; } v; v.f = f;
    uint32_t u = v.u;
    uint32_t r = (u + 0x7FFFu + ((u >> 16) & 1u)) >> 16;   // RNE
    return (unsigned short)r;
}

#define GLL(src, dst) __builtin_amdgcn_global_load_lds(                      \
        (__attribute__((address_space(1))) void*)(src),                      \
        (__attribute__((address_space(3))) void*)(dst), 16, 0, 0)

// ---------------- fp32 -> bf16 convert + PRE-SWIZZLE (4 weight matrices) ----------------
// W_sw[j][kb*8..] = W[j][kbs*8..], kbs = (kb&~7)|((kb^j)&7)
__global__ void cvt_w(const float* __restrict__ wq, const float* __restrict__ wk,
                      const float* __restrict__ wv, const float* __restrict__ wo,
                      unsigned short* __restrict__ dst)
{
    int i = blockIdx.x * 256 + threadIdx.x;      // 16B-block id: 4 * 1024 * 128
    int a = i >> 17;
    int r = i & 131071;
    int j = r >> 7, kb = r & 127;
    int kbs = (kb & ~7) | ((kb ^ j) & 7);
    const float* s = (a == 0 ? wq : a == 1 ? wk : a == 2 ? wv : wo) + (size_t)j * 1024 + kbs * 8;
    float4 f0 = *(const float4*)(s);
    float4 f1 = *(const float4*)(s + 4);
    union { uint32_t u[4]; short8 s8; } c;
    asm("v_cvt_pk_bf16_f32 %0, %1, %2" : "=v"(c.u[0]) : "v"(f0.x), "v"(f0.y));
    asm("v_cvt_pk_bf16_f32 %0, %1, %2" : "=v"(c.u[1]) : "v"(f0.z), "v"(f0.w));
    asm("v_cvt_pk_bf16_f32 %0, %1, %2" : "=v"(c.u[2]) : "v"(f1.x), "v"(f1.y));
    asm("v_cvt_pk_bf16_f32 %0, %1, %2" : "=v"(c.u[3]) : "v"(f1.z), "v"(f1.w));
    *(short8*)(dst + ((size_t)a << 20) + (size_t)j * 1024 + kb * 8) = c.s8;
}

// ---------------- merged QKV GEMM: serial 2-phase, fused fp32-A cvt, 8 waves/block ----------
// Same 128x128 tile / 32KB LDS / swizzle maps as the proven r17 kernel, but 512 threads:
// blocks/CU = min(5 LDS, 4 thread-cap) = 4 -> 32 waves/CU (vs 20) for deeper TLP latency
// hiding across the serial vmcnt(0) drain. Wave grid 4M x 2N, per-wave C = 32x64.
__global__ __launch_bounds__(512) void gemm_qkv(
        const float* __restrict__ Aq, const float* __restrict__ Ak, const float* __restrict__ Av,
        const unsigned short* __restrict__ Wq, const unsigned short* __restrict__ Wk,
        const unsigned short* __restrict__ Wv,
        const float* __restrict__ bq, const float* __restrict__ bk, const float* __restrict__ bv,
        unsigned short* __restrict__ Qo, unsigned short* __restrict__ Ko,
        unsigned short* __restrict__ Vo, const float qscale)
{
    // bijective XCD swizzle: 1536 blocks, 192 contiguous wids/XCD (A-panel + W reuse in L2)
    const int orig = blockIdx.z * 512 + blockIdx.y * 8 + blockIdx.x;
    const int wid  = (orig & 7) * 192 + (orig >> 3);
    const int z    = wid >> 9;
    const int rem  = wid & 511;
    const int brow = (rem >> 3) * 128;
    const int bcol = (rem & 7) * 128;

    const float* A           = (z == 0) ? Aq : (z == 1) ? Ak : Av;
    const unsigned short* Bw = (z == 0) ? Wq : (z == 1) ? Wk : Wv;
    const float* bias        = (z == 0) ? bq : (z == 1) ? bk : bv;

    __shared__ __align__(16) unsigned short lA[128 * 64];
    __shared__ __align__(16) unsigned short lB[128 * 64];
    const int tid = threadIdx.x;
    const int w = tid >> 6, l = tid & 63;          // 8 waves
    const int wr = (w >> 1) * 32, wc = (w & 1) * 64;   // 4M x 2N, per-wave 32x64
    const int lrow = l & 15;
    const int hi = l >> 4;
    const int sr = l >> 3;          // row within 8-row chunk (= row&7)
    const int scb = l & 7;          // 16B-block col
    f32x4 acc[2][4] = {};

    for (int k0 = 0; k0 < 1024; k0 += 64) {
        // B: async global->LDS (pre-swizzled bf16 weights, linear dest); 2 GLLs/thread
#pragma unroll
        for (int i = 0; i < 2; ++i) {
            const int chunk = w * 2 + i;           // 0..15
            const int r = chunk * 8 + sr;
            const unsigned short* gb = Bw + (size_t)(bcol + r) * 1024 + k0 + scb * 8;
            GLL(gb, lB + chunk * 512);
        }
        // A: reg-staged fp32 -> bf16 -> XOR-swizzled LDS write; 2 chunks/thread
#pragma unroll
        for (int i = 0; i < 2; ++i) {
            const int chunk = w * 2 + i;
            const int r = chunk * 8 + sr;
            const float* ga = A + (size_t)(brow + r) * 1024 + k0 + scb * 8;
            float4 f0 = *(const float4*)(ga);
            float4 f1 = *(const float4*)(ga + 4);
            union { uint32_t u[4]; short8 s8; } c;
            asm("v_cvt_pk_bf16_f32 %0, %1, %2" : "=v"(c.u[0]) : "v"(f0.x), "v"(f0.y));
            asm("v_cvt_pk_bf16_f32 %0, %1, %2" : "=v"(c.u[1]) : "v"(f0.z), "v"(f0.w));
            asm("v_cvt_pk_bf16_f32 %0, %1, %2" : "=v"(c.u[2]) : "v"(f1.x), "v"(f1.y));
            asm("v_cvt_pk_bf16_f32 %0, %1, %2" : "=v"(c.u[3]) : "v"(f1.z), "v"(f1.w));
            *(short8*)((char*)lA + chunk * 1024 + sr * 128 + ((scb ^ sr) << 4)) = c.s8;
        }
        asm volatile("s_waitcnt vmcnt(0)" ::: "memory");
        __syncthreads();
#pragma unroll
        for (int kk = 0; kk < 2; ++kk) {
            short8 af[2], bf[4];
#pragma unroll
            for (int m = 0; m < 2; ++m) {
                const int row = wr + m * 16 + lrow;
                const int pb = (kk * 4 + hi) ^ (row & 7);
                af[m] = *(const short8*)((const char*)lA + row * 128 + (pb << 4));
            }
#pragma unroll
            for (int n = 0; n < 4; ++n) {
                const int row = wc + n * 16 + lrow;
                const int pb = (kk * 4 + hi) ^ (row & 7);
                bf[n] = *(const short8*)((const char*)lB + row * 128 + (pb << 4));
            }
#pragma unroll
            for (int m = 0; m < 2; ++m)
#pragma unroll
                for (int n = 0; n < 4; ++n)
                    acc[m][n] = __builtin_amdgcn_mfma_f32_16x16x32_bf16(af[m], bf[n], acc[m][n], 0, 0, 0);
        }
        __syncthreads();
    }

    const float ascale = (z == 0) ? qscale : 1.0f;
#pragma unroll
    for (int m = 0; m < 2; ++m) {
#pragma unroll
        for (int n = 0; n < 4; ++n) {
            const int i0 = brow + wr + m * 16 + hi * 4;
            const int j  = bcol + wc + n * 16 + lrow;
            const float bj = bias[j];
            const int hh = j >> 6, d = j & 63;
            if (z < 2) {
                unsigned short* Cb = (z == 0) ? Qo : Ko;
#pragma unroll
                for (int t = 0; t < 4; ++t) {
                    const int i = i0 + t;
                    const int b = i >> 11, s = i & 2047;
                    Cb[(((size_t)(b * NH + hh) * SS) + s) * DKK + d] = f2bf((acc[m][n][t] + bj) * ascale);
                }
            } else {   // V^T
                const int b = i0 >> 11, s0 = i0 & 2047;
                ushort4 pk;
                pk.x = f2bf(acc[m][n][0] + bj);
                pk.y = f2bf(acc[m][n][1] + bj);
                pk.z = f2bf(acc[m][n][2] + bj);
                pk.w = f2bf(acc[m][n][3] + bj);
                *(ushort4*)(Vo + (((size_t)(b * NH + hh) * DKK) + d) * SS + s0) = pk;
            }
        }
    }
}

// ---------------- final projection GEMM: bf16 A reg-staged swizzled, depth-2, fp32 out ------
__global__ __launch_bounds__(256) void gemm_out(
        const unsigned short* __restrict__ A,
        const unsigned short* __restrict__ Bw,
        const float* __restrict__ bias,
        float* __restrict__ Cout)
{
    const int orig = blockIdx.y * 8 + blockIdx.x;
    const int wid  = (orig & 7) * 64 + (orig >> 3);
    const int brow = (wid >> 3) * 128;
    const int bcol = (wid & 7) * 128;

    __shared__ __align__(16) unsigned short lA[128 * 64];
    __shared__ __align__(16) unsigned short lB[2][128 * 64];

    const int tid = threadIdx.x;
    const int w = tid >> 6, l = tid & 63;
    const int wr = (w >> 1) * 64, wc = (w & 1) * 64;
    const int lrow = l & 15;
    const int hi = l >> 4;
    const int sr = l >> 3, scb = l & 7;

    const unsigned short* aga[4];
    const unsigned short* bga[4];
    int awb[4], lbo[4];
#pragma unroll
    for (int i = 0; i < 4; ++i) {
        const int chunk = w * 4 + i;
        const int r = chunk * 8 + sr;
        aga[i] = A  + (size_t)(brow + r) * 1024 + scb * 8;
        bga[i] = Bw + (size_t)(bcol + r) * 1024 + scb * 8;
        awb[i] = chunk * 1024 + sr * 128 + ((scb ^ sr) << 4);
        lbo[i] = chunk * 512;
    }

    short8 aX[4], aY[4];
    f32x4 acc[4][4] = {};

#pragma unroll
    for (int i = 0; i < 4; ++i) GLL(bga[i], lB[0] + lbo[i]);
#pragma unroll
    for (int i = 0; i < 4; ++i) aX[i] = *(const short8*)(aga[i]);
#pragma unroll
    for (int i = 0; i < 4; ++i) aY[i] = *(const short8*)(aga[i] + 64);

#define OUT_WR(CUR)                                                     \
    _Pragma("unroll")                                                   \
    for (int i = 0; i < 4; ++i)                                         \
        *(short8*)((char*)lA + awb[i]) = CUR[i];

#define OUT_MFMA(LB)                                                                              \
    {                                                                                             \
        const unsigned short* lb = (LB);                                                          \
        __builtin_amdgcn_s_setprio(1);                                                            \
        _Pragma("unroll")                                                                         \
        for (int kk = 0; kk < 2; ++kk) {                                                          \
            short8 af[4], bf[4];                                                                  \
            _Pragma("unroll")                                                                     \
            for (int m = 0; m < 4; ++m) {                                                         \
                const int row = wr + m * 16 + lrow;                                               \
                const int pb = (kk * 4 + hi) ^ (row & 7);                                         \
                af[m] = *(const short8*)((const char*)lA + row * 128 + (pb << 4));                \
            }                                                                                     \
            _Pragma("unroll")                                                                     \
            for (int n = 0; n < 4; ++n) {                                                         \
                const int row = wc + n * 16 + lrow;                                               \
                const int pb = (kk * 4 + hi) ^ (row & 7);                                         \
                bf[n] = *(const short8*)((const char*)lb + row * 128 + (pb << 4));                \
            }                                                                                     \
            _Pragma("unroll")                                                                     \
            for (int m = 0; m < 4; ++m)                                                           \
                _Pragma("unroll")                                                                 \
                for (int n = 0; n < 4; ++n)                                                       \
                    acc[m][n] = __builtin_amdgcn_mfma_f32_16x16x32_bf16(af[m], bf[n], acc[m][n], 0, 0, 0); \
        }                                                                                         \
        __builtin_amdgcn_s_setprio(0);                                                            \
    }

    for (int t = 0; t < 14; t += 2) {
        OUT_WR(aX);
        {
            const int ko = (t + 2) * 64;
#pragma unroll
            for (int i = 0; i < 4; ++i) aX[i] = *(const short8*)(aga[i] + ko);
            const int kb = (t + 1) * 64;
#pragma unroll
            for (int i = 0; i < 4; ++i) GLL(bga[i] + kb, lB[1] + lbo[i]);
        }
        asm volatile("s_waitcnt vmcnt(8) lgkmcnt(0)" ::: "memory");
        __builtin_amdgcn_s_barrier();
        OUT_MFMA(lB[0]);
        asm volatile("" ::: "memory");
        __builtin_amdgcn_s_barrier();

        OUT_WR(aY);
        {
            const int ko = (t + 3) * 64;
#pragma unroll
            for (int i = 0; i < 4; ++i) aY[i] = *(const short8*)(aga[i] + ko);
            const int kb = (t + 2) * 64;
#pragma unroll
            for (int i = 0; i < 4; ++i) GLL(bga[i] + kb, lB[0] + lbo[i]);
        }
        asm volatile("s_waitcnt vmcnt(8) lgkmcnt(0)" ::: "memory");
        __builtin_amdgcn_s_barrier();
        OUT_MFMA(lB[1]);
        asm volatile("" ::: "memory");
        __builtin_amdgcn_s_barrier();
    }
    OUT_WR(aX);
#pragma unroll
    for (int i = 0; i < 4; ++i) GLL(bga[i] + 15 * 64, lB[1] + lbo[i]);
    asm volatile("s_waitcnt vmcnt(4) lgkmcnt(0)" ::: "memory");
    __builtin_amdgcn_s_barrier();
    OUT_MFMA(lB[0]);
    asm volatile("" ::: "memory");
    __builtin_amdgcn_s_barrier();
    OUT_WR(aY);
    asm volatile("s_waitcnt vmcnt(0) lgkmcnt(0)" ::: "memory");
    __builtin_amdgcn_s_barrier();
    OUT_MFMA(lB[1]);

#pragma unroll
    for (int m = 0; m < 4; ++m) {
#pragma unroll
        for (int n = 0; n < 4; ++n) {
            const int i0 = brow + wr + m * 16 + (l >> 4) * 4;
            const int j  = bcol + wc + n * 16 + lrow;
            const float bj = bias[j];
#pragma unroll
            for (int t = 0; t < 4; ++t)
                Cout[(size_t)(i0 + t) * DM + j] = acc[m][n][t] + bj;
        }
    }
#undef OUT_WR
#undef OUT_MFMA
}

// ---------------- causal flash attention (round-7, unchanged) ----------------
__global__ __launch_bounds__(256) void attn_kernel(
        const unsigned short* __restrict__ Q,
        const unsigned short* __restrict__ K,
        const unsigned short* __restrict__ Vt,
        unsigned short* __restrict__ AO)
{
    const int flat = blockIdx.y * 16 + blockIdx.x;      // grid (16, 64)
    const int r8 = flat & 7, k8 = flat >> 3;
    const int bh = r8 * 8 + (k8 & 7);                   // 8 heads per XCD-residue (L2 share)
    const int qchunk = 15 - (k8 >> 3);                  // LPT: long blocks first
    const int tid = threadIdx.x;
    const int w = tid >> 6, l = tid & 63;
    const int ln = l & 31, h = l >> 5;
    const int qb = qchunk * 128;
    const int q0w = qb + w * 32;

    __shared__ __align__(16) char lK[2][4096];
    __shared__ __align__(16) char lV[2][4096];

    const unsigned short* Qp = Q  + ((size_t)bh * SS + q0w) * DKK;
    const unsigned short* Kp = K  + (size_t)bh * SS * DKK;
    const unsigned short* Vp = Vt + (size_t)bh * DKK * SS;

    const int srow = tid >> 3, scb = tid & 7;
    const int swb = srow * 128 + ((scb * 16) ^ ((srow & 7) << 4));
    const unsigned short* ksrc = Kp + srow * DKK + scb * 8;            // + t*2048
    const int vd = (scb < 4) ? srow : (srow + 32);
    const unsigned short* vsrc = Vp + (size_t)vd * SS + (scb & 3) * 8; // + t*32

    int ka[4], va[4];
#pragma unroll
    for (int ks = 0; ks < 4; ++ks)
        ka[ks] = ln * 128 + ((ks * 32 + h * 16) ^ ((ln & 7) << 4));
#pragma unroll
    for (int c = 0; c < 4; ++c)
        va[c] = ln * 128 + ((c * 32 + h * 16) ^ ((ln & 7) << 4));

    short8 qf[4];
#pragma unroll
    for (int ks = 0; ks < 4; ++ks)
        qf[ks] = *(const short8*)(Qp + (size_t)ln * DKK + ks * 16 + h * 8);

    f32x16 o0 = {}, o1 = {};
    float lsum = 0.f;

    const int Tc = qb / 32;
    const int NT = Tc + 4;

    auto compute = [&](int t, int buf) {
        const char* kb = lK[buf];
        const char* vb = lV[buf];
        short8 kf[4];
#pragma unroll
        for (int ks = 0; ks < 4; ++ks) kf[ks] = *(const short8*)(kb + ka[ks]);

        f32x16 s = {};
        __builtin_amdgcn_s_setprio(1);
#pragma unroll
        for (int ks = 0; ks < 4; ++ks)
            s = __builtin_amdgcn_mfma_f32_32x32x16_bf16(kf[ks], qf[ks], s, 0, 0, 0);
        __builtin_amdgcn_s_setprio(0);

        const bool diag = (t == Tc + w);
#pragma unroll
        for (int r = 0; r < 16; ++r) {
            float e;
            asm("v_exp_f32 %0, %1" : "=v"(e) : "v"(s[r]));   // 2^s (Q pre-scaled)
            if (diag) {
                const int crow = (r & 3) + 8 * (r >> 2) + 4 * h;
                e = (crow > ln) ? 0.f : e;
            }
            s[r] = e;
            lsum += e;
        }

        uint32_t pk[8];
#pragma unroll
        for (int i = 0; i < 8; ++i) {
            uint32_t d;
            asm("v_cvt_pk_bf16_f32 %0, %1, %2" : "=v"(d) : "v"(s[2 * i]), "v"(s[2 * i + 1]));
            pk[i] = d;
        }
        asm("v_permlane32_swap_b32 %0, %1" : "+v"(pk[0]), "+v"(pk[2]));
        asm("v_permlane32_swap_b32 %0, %1" : "+v"(pk[1]), "+v"(pk[3]));
        asm("v_permlane32_swap_b32 %0, %1" : "+v"(pk[4]), "+v"(pk[6]));
        asm("v_permlane32_swap_b32 %0, %1" : "+v"(pk[5]), "+v"(pk[7]));

        union Ux { uint32_t u[4]; short8 s8; } pa0, pa1;
        pa0.u[0] = pk[0]; pa0.u[1] = pk[1]; pa0.u[2] = pk[2]; pa0.u[3] = pk[3];
        pa1.u[0] = pk[4]; pa1.u[1] = pk[5]; pa1.u[2] = pk[6]; pa1.u[3] = pk[7];

        short8 vf00 = *(const short8*)(vb + va[0]);
        short8 vf10 = *(const short8*)(vb + va[1]);
        short8 vf01 = *(const short8*)(vb + va[2]);
        short8 vf11 = *(const short8*)(vb + va[3]);

        __builtin_amdgcn_s_setprio(1);
        o0 = __builtin_amdgcn_mfma_f32_32x32x16_bf16(pa0.s8, vf00, o0, 0, 0, 0);
        o0 = __builtin_amdgcn_mfma_f32_32x32x16_bf16(pa1.s8, vf10, o0, 0, 0, 0);
        o1 = __builtin_amdgcn_mfma_f32_32x32x16_bf16(pa0.s8, vf01, o1, 0, 0, 0);
        o1 = __builtin_amdgcn_mfma_f32_32x32x16_bf16(pa1.s8, vf11, o1, 0, 0, 0);
        __builtin_amdgcn_s_setprio(0);
    };

    short8 kA = *(const short8*)(ksrc);
    short8 vA = *(const short8*)(vsrc);
    *(short8*)(&lK[0][swb]) = kA;
    *(short8*)(&lV[0][swb]) = vA;
    kA = *(const short8*)(ksrc + 2048);
    vA = *(const short8*)(vsrc + 32);
    short8 kB = {}, vB = {};
    __syncthreads();

    int t = 0, buf = 0;
    for (;;) {
        if (t + 2 < NT) {
            kB = *(const short8*)(ksrc + (size_t)(t + 2) * 2048);
            vB = *(const short8*)(vsrc + (size_t)(t + 2) * 32);
        }
        if (t <= Tc + w) compute(t, buf);
        if (t + 1 < NT) {
            *(short8*)(&lK[buf ^ 1][swb]) = kA;
            *(short8*)(&lV[buf ^ 1][swb]) = vA;
        }
        __syncthreads();
        buf ^= 1;
        if (++t == NT) break;

        if (t + 2 < NT) {
            kA = *(const short8*)(ksrc + (size_t)(t + 2) * 2048);
            vA = *(const short8*)(vsrc + (size_t)(t + 2) * 32);
        }
        if (t <= Tc + w) compute(t, buf);
        if (t + 1 < NT) {
            *(short8*)(&lK[buf ^ 1][swb]) = kB;
            *(short8*)(&lV[buf ^ 1][swb]) = vB;
        }
        __syncthreads();
        buf ^= 1;
        if (++t == NT) break;
    }

    lsum += __shfl_xor(lsum, 32, 64);
    const float rcp = 1.0f / lsum;

    const int bb = bh >> 4, hh = bh & 15;
#pragma unroll
    for (int r = 0; r < 16; ++r) {
        const int crow = (r & 3) + 8 * (r >> 2) + 4 * h;
        const float rl = __shfl(rcp, crow, 64);
        const size_t row = (size_t)(bb * SS + q0w + crow) * DM + hh * DKK;
        AO[row + ln]      = f2bf(o0[r] * rl);
        AO[row + 32 + ln] = f2bf(o1[r] * rl);
    }
}

extern "C" void kernel_launch(void* const* d_in, const int* in_sizes, int n_in,
                              void* d_out, int out_size, void* d_ws, size_t ws_size,
                              hipStream_t stream)
{
    const float* query  = (const float*)d_in[0];
    const float* key_in = (const float*)d_in[1];
    const float* value  = (const float*)d_in[2];
    const float* Wq = (const float*)d_in[3];
    const float* bq = (const float*)d_in[4];
    const float* Wk = (const float*)d_in[5];
    const float* bk = (const float*)d_in[6];
    const float* Wv = (const float*)d_in[7];
    const float* bv = (const float*)d_in[8];
    const float* Wo = (const float*)d_in[9];
    const float* bo = (const float*)d_in[10];

    const size_t NACT = (size_t)BB * SS * DM;   // 8388608
    const size_t NWT  = (size_t)DM * DM;        // 1048576

    unsigned short* ws  = (unsigned short*)d_ws;
    unsigned short* wqb = ws;
    unsigned short* wkb = wqb + NWT;
    unsigned short* wvb = wkb + NWT;
    unsigned short* wob = wvb + NWT;
    unsigned short* Qb  = wob + NWT;
    unsigned short* Kb  = Qb + NACT;
    unsigned short* Vtb = Kb + NACT;
    unsigned short* AOb = Vtb + NACT;

    cvt_w<<<2048, 256, 0, stream>>>(Wq, Wk, Wv, Wo, ws);

    const float QSCALE = 0.125f * 1.44269504088896f;   // 1/sqrt(64) * log2(e)
    dim3 gq(8, 64, 3);   // 1536 blocks
    gemm_qkv<<<gq, 512, 0, stream>>>(query, key_in, value, wqb, wkb, wvb,
                                     bq, bk, bv, Qb, Kb, Vtb, QSCALE);

    attn_kernel<<<dim3(16, 64), 256, 0, stream>>>(Qb, Kb, Vtb, AOb);

    dim3 gg(DM / 128, (BB * SS) / 128);   // (8, 64)
    gemm_out<<<gg, 256, 0, stream>>>(AOb, wob, bo, (float*)d_out);
}